// Round 8
// baseline (249.221 us; speedup 1.0000x reference)
//
#include <hip/hip_runtime.h>
#include <hip/hip_bf16.h>
#include <math.h>

// Problem constants
#define NB   4096      // graphs
#define MM   64        // points per graph
#define KNN  3
#define FX   59
#define H    128
#define NN   (NB*MM)       // 262144 nodes
#define NE   (NN*KNN)      // 786432 edges
#define C1   256
#define EPSB 1e-5f
#define NSH  16            // atomic shadow copies (contention = NB/NSH per addr)

typedef __attribute__((ext_vector_type(8))) short short8;   // 8 bf16 (4 VGPRs)
typedef __attribute__((ext_vector_type(4))) float f32x4;

__device__ __forceinline__ float wave_red(float v) {
#pragma unroll
    for (int m = 32; m >= 1; m >>= 1) v += __shfl_xor(v, m, 64);
    return v;
}

__device__ __forceinline__ void atomAddF(float* p, float v) {
    __hip_atomic_fetch_add(p, v, __ATOMIC_RELAXED, __HIP_MEMORY_SCOPE_AGENT);
}

__device__ __forceinline__ unsigned short f2bf(float f) {
    union { float f; unsigned u; } v; v.f = f;
    unsigned r = v.u + 0x7fffu + ((v.u >> 16) & 1u);   // round-to-nearest-even
    return (unsigned short)(r >> 16);
}

// pack two f32 -> u32 of 2 bf16 (lo = a, hi = b), RNE (v_cvt_pk_bf16_f32)
__device__ __forceinline__ unsigned int pack_bf2(float a, float b) {
    union { __hip_bfloat162 h; unsigned int u; } cv;
    cv.h = __float22bfloat162_rn(make_float2(a, b));
    return cv.u;
}

// ---------------------------------------------------------------------------
// K1, edge-matrix form (r7) + conflict fixes (r8):
//  - a_s granule rotation slot=(g-node)&7: E-gather read banks become 4g
//    (uniform) instead of j-dependent.
//  - BN1 partials: shfl_xor over m-bits (intra-wave) + direct shadow atomics.
//    Replaces the red-LDS round-trip whose read (red[tid*16+mm]) was a
//    32-way bank conflict x16 (the bulk of r7's 6.5M conflict cycles).
// 512 thr / 8 waves; LDS 38.9 KB -> 4 blocks/CU (32 waves, at wave cap).
// ---------------------------------------------------------------------------
__global__ __launch_bounds__(512, 8) void k_knn_mfma1(
    const float* __restrict__ x, const float* __restrict__ pos,
    const float* __restrict__ W1, const float* __restrict__ b1,
    unsigned short* __restrict__ h1max,
    float* __restrict__ S1sh, float* __restrict__ Q1sh)
{
    __shared__ float pos_s[MM * 3];
    __shared__ int   nbr_s[MM * 3];
    __shared__ float b1_s[H];
    __shared__ __align__(16) unsigned short a_s[MM * 72];       // [x|p|0,0], granule-rotated
    __shared__ __align__(16) unsigned short e_s[3 * MM * 72];   // edge features, linear

    const int blk = blockIdx.x, tid = threadIdx.x;
    const float* xg = x + (size_t)blk * MM * FX;
    const float* pg = pos + (size_t)blk * MM * 3;

    // --- prepx: thread = one 16B granule of a node row; rotated store
    {
        const int node = tid >> 3, g = tid & 7;
        const int c0g = g * 8;
        float v[8];
#pragma unroll
        for (int i = 0; i < 8; ++i) {
            int cI = c0g + i;
            v[i] = (cI < FX) ? xg[node * FX + cI]
                             : ((cI < 62) ? pg[node * 3 + (cI - FX)] : 0.f);
        }
        uint4 pk;
        pk.x = pack_bf2(v[0], v[1]); pk.y = pack_bf2(v[2], v[3]);
        pk.z = pack_bf2(v[4], v[5]); pk.w = pack_bf2(v[6], v[7]);
        const int gs = (g - node) & 7;                  // rotation
        *(uint4*)(a_s + node * 72 + gs * 8) = pk;
    }
    if (tid < MM * 3) pos_s[tid] = pg[tid];
    if (tid < H) b1_s[tid] = b1[tid];

    // --- W1 fragments straight from global (L2-hot)
    const int lane = tid & 63;
    const int w    = tid >> 6;          // 8 waves
    const int m    = lane & 15;
    const int kg   = lane >> 4;
    const int ch   = w * 16 + m;        // wave owns channels [w*16, w*16+16)

    short8 bfr[2];
#pragma unroll
    for (int kc = 0; kc < 2; ++kc) {
        float t8[8];
#pragma unroll
        for (int i = 0; i < 8; ++i) {
            int k = kc * 32 + kg * 8 + i;
            t8[i] = (k < 62) ? W1[k * H + ch] : 0.f;
        }
        uint4 pk;
        pk.x = pack_bf2(t8[0], t8[1]); pk.y = pack_bf2(t8[2], t8[3]);
        pk.z = pack_bf2(t8[4], t8[5]); pk.w = pack_bf2(t8[6], t8[7]);
        bfr[kc] = *(short8*)&pk;
    }
    __syncthreads();    // a_s, pos_s ready

    // --- parallel kNN: 8 threads per node, each scans 8 candidates; merge
    //     via shfl_xor(1,2,4). Lexicographic (d, idx) == top_k tie-break.
    {
        const int node = tid >> 3, q = tid & 7;
        const float px = pos_s[node * 3 + 0];
        const float py = pos_s[node * 3 + 1];
        const float pz = pos_s[node * 3 + 2];
        float d0 = 1e30f, d1 = 1e30f, d2 = 1e30f;
        int   i0 = 1 << 30, i1 = 1 << 30, i2 = 1 << 30;
        for (int jj = 0; jj < 8; ++jj) {
            int j = q * 8 + jj;
            if (j == node) continue;
            float dx = pos_s[j * 3 + 0] - px;
            float dy = pos_s[j * 3 + 1] - py;
            float dz = pos_s[j * 3 + 2] - pz;
            float d = dx * dx + dy * dy + dz * dz;
            bool b2v = (d < d2) || (d == d2 && j < i2);
            bool b1v = (d < d1) || (d == d1 && j < i1);
            bool b0v = (d < d0) || (d == d0 && j < i0);
            float nd2 = b1v ? d1 : d; int ni2 = b1v ? i1 : j;
            float nd1 = b0v ? d0 : d; int ni1 = b0v ? i0 : j;
            d2 = b2v ? nd2 : d2; i2 = b2v ? ni2 : i2;
            d1 = b1v ? nd1 : d1; i1 = b1v ? ni1 : i1;
            d0 = b0v ? d   : d0; i0 = b0v ? j   : i0;
        }
#pragma unroll
        for (int mq = 1; mq <= 4; mq <<= 1) {
            float e[3]; int f[3];
            e[0] = __shfl_xor(d0, mq, 64); f[0] = __shfl_xor(i0, mq, 64);
            e[1] = __shfl_xor(d1, mq, 64); f[1] = __shfl_xor(i1, mq, 64);
            e[2] = __shfl_xor(d2, mq, 64); f[2] = __shfl_xor(i2, mq, 64);
#pragma unroll
            for (int t3 = 0; t3 < 3; ++t3) {
                float ev = e[t3]; int fv = f[t3];
                bool b2v = (ev < d2) || (ev == d2 && fv < i2);
                bool b1v = (ev < d1) || (ev == d1 && fv < i1);
                bool b0v = (ev < d0) || (ev == d0 && fv < i0);
                float nd2 = b1v ? d1 : ev; int ni2 = b1v ? i1 : fv;
                float nd1 = b0v ? d0 : ev; int ni1 = b0v ? i0 : fv;
                d2 = b2v ? nd2 : d2; i2 = b2v ? ni2 : i2;
                d1 = b1v ? nd1 : d1; i1 = b1v ? ni1 : i1;
                d0 = b0v ? ev  : d0; i0 = b0v ? fv  : i0;
            }
        }
        if (q == 0) {
            nbr_s[node * 3 + 0] = i0;
            nbr_s[node * 3 + 1] = i1;
            nbr_s[node * 3 + 2] = i2;
        }
    }
    __syncthreads();    // nbr_s ready

    // --- E-build: row (slot*64+node) = a_s[j] (rotated read, banks = 4g)
    //     with cols 59..61 patched to bf16(p_j - p_i), cols 62,63 = 0.
#pragma unroll
    for (int it = 0; it < 3; ++it) {
        const int T = tid + it * 512;
        const int row = T >> 3, g = T & 7;
        const int node = row & 63, slot = row >> 6;
        const int j = nbr_s[node * 3 + slot];
        const int gs = (g - j) & 7;                     // rotated source slot
        if (g < 7) {
            *(uint4*)(e_s + row * 72 + g * 8) = *(const uint4*)(a_s + j * 72 + gs * 8);
        } else {
            uint4 v = *(const uint4*)(a_s + j * 72 + gs * 8);   // cols 56..63
            float r0 = pos_s[j * 3 + 0] - pos_s[node * 3 + 0];
            float r1 = pos_s[j * 3 + 1] - pos_s[node * 3 + 1];
            float r2 = pos_s[j * 3 + 2] - pos_s[node * 3 + 2];
            v.y = (v.y & 0xffffu) | ((unsigned)f2bf(r0) << 16);  // col59 (58 kept)
            v.z = pack_bf2(r1, r2);                              // cols 60,61
            v.w = 0u;                                            // cols 62,63
            *(uint4*)(e_s + row * 72 + 56) = v;
        }
    }
    __syncthreads();    // e_s ready

    // --- MFMA E@W1 per node-group; in-register relu/max/stats epilogue.
    const int cb = w * 16 + kg * 4;          // 4 consecutive channels per lane
    const float b1v0 = b1_s[cb + 0], b1v1 = b1_s[cb + 1];
    const float b1v2 = b1_s[cb + 2], b1v3 = b1_s[cb + 3];
    float s0 = 0.f, s1 = 0.f, s2 = 0.f, s3 = 0.f;
    float q0 = 0.f, q1 = 0.f, q2 = 0.f, q3 = 0.f;
    unsigned int* hout32 = (unsigned int*)(h1max + (size_t)blk * MM * H);
#pragma unroll
    for (int rt4 = 0; rt4 < 4; ++rt4) {
        const int node = rt4 * 16 + m;
        f32x4 acc0 = (f32x4){0.f,0.f,0.f,0.f};
        f32x4 acc1 = (f32x4){0.f,0.f,0.f,0.f};
        f32x4 acc2 = (f32x4){0.f,0.f,0.f,0.f};
#pragma unroll
        for (int kc = 0; kc < 2; ++kc) {
            const int ko = kc * 32 + kg * 8;
            short8 a0 = *(const short8*)(e_s + (node      ) * 72 + ko);
            short8 a1 = *(const short8*)(e_s + (node +  64) * 72 + ko);
            short8 a2 = *(const short8*)(e_s + (node + 128) * 72 + ko);
            acc0 = __builtin_amdgcn_mfma_f32_16x16x32_bf16(bfr[kc], a0, acc0, 0, 0, 0);
            acc1 = __builtin_amdgcn_mfma_f32_16x16x32_bf16(bfr[kc], a1, acc1, 0, 0, 0);
            acc2 = __builtin_amdgcn_mfma_f32_16x16x32_bf16(bfr[kc], a2, acc2, 0, 0, 0);
        }
        float hm0, hm1, hm2, hm3;
        {
            float ha = fmaxf(acc0[0] + b1v0, 0.f), hb = fmaxf(acc1[0] + b1v0, 0.f), hc = fmaxf(acc2[0] + b1v0, 0.f);
            s0 += ha + hb + hc; q0 += ha * ha + hb * hb + hc * hc; hm0 = fmaxf(fmaxf(ha, hb), hc);
        }
        {
            float ha = fmaxf(acc0[1] + b1v1, 0.f), hb = fmaxf(acc1[1] + b1v1, 0.f), hc = fmaxf(acc2[1] + b1v1, 0.f);
            s1 += ha + hb + hc; q1 += ha * ha + hb * hb + hc * hc; hm1 = fmaxf(fmaxf(ha, hb), hc);
        }
        {
            float ha = fmaxf(acc0[2] + b1v2, 0.f), hb = fmaxf(acc1[2] + b1v2, 0.f), hc = fmaxf(acc2[2] + b1v2, 0.f);
            s2 += ha + hb + hc; q2 += ha * ha + hb * hb + hc * hc; hm2 = fmaxf(fmaxf(ha, hb), hc);
        }
        {
            float ha = fmaxf(acc0[3] + b1v3, 0.f), hb = fmaxf(acc1[3] + b1v3, 0.f), hc = fmaxf(acc2[3] + b1v3, 0.f);
            s3 += ha + hb + hc; q3 += ha * ha + hb * hb + hc * hc; hm3 = fmaxf(fmaxf(ha, hb), hc);
        }
        uint2 val;
        val.x = pack_bf2(hm0, hm1);
        val.y = pack_bf2(hm2, hm3);
        *(uint2*)(hout32 + node * 64 + w * 8 + kg * 2) = val;
    }

    // --- BN1 partials: reduce over the 16 m-lanes in-register (m = lane bits
    //     0..3), then m==0 lanes add their 4 channels to the shadow copies.
#pragma unroll
    for (int mk = 1; mk <= 8; mk <<= 1) {
        s0 += __shfl_xor(s0, mk, 64); s1 += __shfl_xor(s1, mk, 64);
        s2 += __shfl_xor(s2, mk, 64); s3 += __shfl_xor(s3, mk, 64);
        q0 += __shfl_xor(q0, mk, 64); q1 += __shfl_xor(q1, mk, 64);
        q2 += __shfl_xor(q2, mk, 64); q3 += __shfl_xor(q3, mk, 64);
    }
    if (m == 0) {
        const int sel = blk & (NSH - 1);
        atomAddF(&S1sh[sel * H + cb + 0], s0);
        atomAddF(&S1sh[sel * H + cb + 1], s1);
        atomAddF(&S1sh[sel * H + cb + 2], s2);
        atomAddF(&S1sh[sel * H + cb + 3], s3);
        atomAddF(&Q1sh[sel * H + cb + 0], q0);
        atomAddF(&Q1sh[sel * H + cb + 1], q1);
        atomAddF(&Q1sh[sel * H + cb + 2], q2);
        atomAddF(&Q1sh[sel * H + cb + 3], q3);
    }
}

// ---------------------------------------------------------------------------
// prep2: fold 16 BN1 shadows -> affine1 in-register; emit W2t (affine folded)
// and b2p. grid=128, blk=128.
// ---------------------------------------------------------------------------
__global__ __launch_bounds__(128) void k_prep2(
    const float* __restrict__ W2, const float* __restrict__ S1sh,
    const float* __restrict__ Q1sh, const float* __restrict__ g1,
    const float* __restrict__ be1, const float* __restrict__ b2,
    unsigned short* __restrict__ W2t, float* __restrict__ b2p)
{
    const int n = blockIdx.x, k = threadIdx.x;
    float S = 0.f, Q = 0.f;
#pragma unroll
    for (int i = 0; i < NSH; ++i) { S += S1sh[i * H + k]; Q += Q1sh[i * H + k]; }
    float mu  = S * (1.f / (float)NE);
    float var = Q * (1.f / (float)NE) - mu * mu;
    float a   = g1[k] * rsqrtf(var + EPSB);
    float cc  = be1[k] - mu * a;
    float wv  = W2[k * H + n];
    W2t[n * H + k] = f2bf(a * wv);
    float contrib = wave_red(cc * wv);
    __shared__ float red2[2];
    if ((k & 63) == 0) red2[k >> 6] = contrib;
    __syncthreads();
    if (k == 0) b2p[n] = b2[n] + red2[0] + red2[1];
}

// ---------------------------------------------------------------------------
// K3: h2 = relu(h1max(bf16) @ W2t + b2p) via MFMA; graphsum + shadowed
// atomic BN2 stats. LDS-staged. grid=4096, 256 thr.
// ---------------------------------------------------------------------------
__global__ __launch_bounds__(256) void k_mfma2(
    const unsigned short* __restrict__ h1max, const unsigned short* __restrict__ W2t,
    const float* __restrict__ b2p,
    float* __restrict__ graphsum, float* __restrict__ S2sh, float* __restrict__ Q2sh)
{
    __shared__ __align__(16) unsigned short a_s[MM * 136];  // 64x128 bf16, stride 136
    const int blk = blockIdx.x, tid = threadIdx.x;
    const unsigned short* hg = h1max + (size_t)blk * MM * H;
    for (int t = tid; t < MM * H / 8; t += 256) {
        int row = t >> 4, col8 = (t & 15) * 8;
        *(short8*)(a_s + row * 136 + col8) = *(const short8*)(hg + row * H + col8);
    }
    __syncthreads();

    const int lane = tid & 63, w = tid >> 6, wcol = w * 32;
    const int m = lane & 15, kg = lane >> 4;

    short8 bfr[2][4];
#pragma unroll
    for (int ct = 0; ct < 2; ++ct)
#pragma unroll
        for (int kc = 0; kc < 4; ++kc)
            bfr[ct][kc] = *(const short8*)(W2t + (wcol + ct * 16 + m) * H + kc * 32 + kg * 8);

    f32x4 acc[4][2];
#pragma unroll
    for (int rt = 0; rt < 4; ++rt)
#pragma unroll
        for (int ct = 0; ct < 2; ++ct) acc[rt][ct] = (f32x4){0.f, 0.f, 0.f, 0.f};

#pragma unroll
    for (int kc = 0; kc < 4; ++kc)
#pragma unroll
        for (int rt = 0; rt < 4; ++rt) {
            short8 a = *(const short8*)(a_s + (rt * 16 + m) * 136 + kc * 32 + kg * 8);
#pragma unroll
            for (int ct = 0; ct < 2; ++ct)
                acc[rt][ct] = __builtin_amdgcn_mfma_f32_16x16x32_bf16(a, bfr[ct][kc], acc[rt][ct], 0, 0, 0);
        }

    const int sel = blk & (NSH - 1);
#pragma unroll
    for (int ct = 0; ct < 2; ++ct) {
        float bv = b2p[wcol + ct * 16 + m];
        float s = 0.f, q = 0.f;
#pragma unroll
        for (int rt = 0; rt < 4; ++rt)
#pragma unroll
            for (int r = 0; r < 4; ++r) {
                float v = fmaxf(acc[rt][ct][r] + bv, 0.f);
                s += v; q += v * v;
            }
        s += __shfl_xor(s, 16, 64); q += __shfl_xor(q, 16, 64);
        s += __shfl_xor(s, 32, 64); q += __shfl_xor(q, 32, 64);
        if (lane < 16) {
            int col = wcol + ct * 16 + lane;
            graphsum[(size_t)blk * H + col] = s;
            atomAddF(&S2sh[sel * H + col], s);
            atomAddF(&Q2sh[sel * H + col], q);
        }
    }
}

// ---------------------------------------------------------------------------
// cls1: affine2 inline from shadows; pooled = BN2(graphsum/64);
// c1 = ReLU(pooled @ Wc1 + bc1); BN3 stats via direct atomics.
// grid=256, blk=256 (16 graphs per block).
// ---------------------------------------------------------------------------
__global__ __launch_bounds__(256) void k_cls1(
    const float* __restrict__ graphsum,
    const float* __restrict__ S2sh, const float* __restrict__ Q2sh,
    const float* __restrict__ g2, const float* __restrict__ be2,
    const float* __restrict__ Wc1, const float* __restrict__ bc1,
    float* __restrict__ c1raw, float* __restrict__ S3, float* __restrict__ Q3)
{
    __shared__ float a2_s[H], c2_s[H];
    const int blk = blockIdx.x, tid = threadIdx.x;
    if (tid < H) {
        float S = 0.f, Q = 0.f;
#pragma unroll
        for (int i = 0; i < NSH; ++i) { S += S2sh[i * H + tid]; Q += Q2sh[i * H + tid]; }
        float mu  = S * (1.f / (float)NN);
        float var = Q * (1.f / (float)NN) - mu * mu;
        float a   = g2[tid] * rsqrtf(var + EPSB);
        a2_s[tid] = a;
        c2_s[tid] = be2[tid] - mu * a;
    }
    __syncthreads();
    __shared__ float pooled_s[16 * H];
    const int g0 = blk * 16;
    for (int t = tid; t < 16 * H; t += 256) {
        int f = t & 127;
        pooled_s[t] = a2_s[f] * (graphsum[(size_t)g0 * H + t] * (1.f / 64.f)) + c2_s[f];
    }
    __syncthreads();
    const int c = tid;
    float acc[16];
    const float bias = bc1[c];
#pragma unroll
    for (int gi = 0; gi < 16; ++gi) acc[gi] = bias;
    for (int f = 0; f < H; ++f) {
        float wv = Wc1[f * C1 + c];
#pragma unroll
        for (int gi = 0; gi < 16; ++gi) acc[gi] += pooled_s[gi * H + f] * wv;
    }
    float s = 0.f, q = 0.f;
#pragma unroll
    for (int gi = 0; gi < 16; ++gi) {
        float h = fmaxf(acc[gi], 0.f);
        c1raw[(size_t)(g0 + gi) * C1 + c] = h;
        s += h; q += h * h;
    }
    atomAddF(&S3[c], s);
    atomAddF(&Q3[c], q);
}

// ---------------------------------------------------------------------------
// cls2: affine3 inline from S3/Q3; z = ReLU(BN3(c1) @ Wc2 + bc2);
// final-BN scalar stats via atomics. grid=256, blk=256 (16 lanes/graph).
// ---------------------------------------------------------------------------
__global__ __launch_bounds__(256) void k_cls2(
    const float* __restrict__ c1raw,
    const float* __restrict__ S3, const float* __restrict__ Q3,
    const float* __restrict__ gc1, const float* __restrict__ bec1,
    const float* __restrict__ Wc2, const float* __restrict__ bc2,
    float* __restrict__ z, float* __restrict__ SzQz)
{
    __shared__ float a3_s[C1], c3_s[C1], w3_s[C1];
    __shared__ float zloc[16];
    const int blk = blockIdx.x, tid = threadIdx.x;
    {
        float S = S3[tid], Q = Q3[tid];
        float mu  = S * (1.f / (float)NB);
        float var = Q * (1.f / (float)NB) - mu * mu;
        float a   = gc1[tid] * rsqrtf(var + EPSB);
        a3_s[tid] = a;
        c3_s[tid] = bec1[tid] - mu * a;
        w3_s[tid] = Wc2[tid];
    }
    __syncthreads();
    const int g0 = blk * 16;
    {
        const int gi = tid >> 4, part = tid & 15;
        const float* crow = c1raw + (size_t)(g0 + gi) * C1 + part * 16;
        float acc3 = 0.f;
#pragma unroll
        for (int i = 0; i < 16; i += 4) {
            float4 cv = *(const float4*)(crow + i);
            int f = part * 16 + i;
            acc3 += (a3_s[f + 0] * cv.x + c3_s[f + 0]) * w3_s[f + 0];
            acc3 += (a3_s[f + 1] * cv.y + c3_s[f + 1]) * w3_s[f + 1];
            acc3 += (a3_s[f + 2] * cv.z + c3_s[f + 2]) * w3_s[f + 2];
            acc3 += (a3_s[f + 3] * cv.w + c3_s[f + 3]) * w3_s[f + 3];
        }
#pragma unroll
        for (int mm = 1; mm <= 8; mm <<= 1) acc3 += __shfl_xor(acc3, mm, 64);
        if (part == 0) zloc[gi] = fmaxf(acc3 + bc2[0], 0.f);
    }
    __syncthreads();
    if (tid < 16) z[g0 + tid] = zloc[tid];
    if (tid == 0) {
        float s = 0.f, q = 0.f;
#pragma unroll
        for (int i = 0; i < 16; ++i) { float zz = zloc[i]; s += zz; q += zz * zz; }
        atomAddF(&SzQz[0], s);
        atomAddF(&SzQz[1], q);
    }
}

// ---------------------------------------------------------------------------
// final: BN over 4096 z (stats from SzQz) + sigmoid. grid=16, blk=256.
// ---------------------------------------------------------------------------
__global__ __launch_bounds__(256) void k_final(
    const float* __restrict__ z, const float* __restrict__ SzQz,
    const float* __restrict__ gc2, const float* __restrict__ bec2,
    float* __restrict__ out)
{
    const int g = blockIdx.x * 256 + threadIdx.x;
    float S = SzQz[0], Q = SzQz[1];
    float mu  = S * (1.f / 4096.f);
    float var = Q * (1.f / 4096.f) - mu * mu;
    float a   = gc2[0] * rsqrtf(var + EPSB);
    float cb  = bec2[0] - mu * a;
    float v = a * z[g] + cb;
    out[g] = 1.f / (1.f + expf(-v));
}

extern "C" void kernel_launch(void* const* d_in, const int* in_sizes, int n_in,
                              void* d_out, int out_size, void* d_ws, size_t ws_size,
                              hipStream_t stream)
{
    const float* x    = (const float*)d_in[0];
    const float* pos  = (const float*)d_in[1];
    // d_in[2] = batch (int32) — graphs are contiguous 64-node chunks; unused
    const float* W1   = (const float*)d_in[3];
    const float* b1   = (const float*)d_in[4];
    const float* g1   = (const float*)d_in[5];
    const float* be1  = (const float*)d_in[6];
    const float* W2   = (const float*)d_in[7];
    const float* b2   = (const float*)d_in[8];
    const float* g2   = (const float*)d_in[9];
    const float* be2  = (const float*)d_in[10];
    const float* Wc1  = (const float*)d_in[11];
    const float* bc1  = (const float*)d_in[12];
    const float* gc1  = (const float*)d_in[13];
    const float* bec1 = (const float*)d_in[14];
    const float* Wc2  = (const float*)d_in[15];
    const float* bc2  = (const float*)d_in[16];
    const float* gc2  = (const float*)d_in[17];
    const float* bec2 = (const float*)d_in[18];
    float* out = (float*)d_out;

    float* ws = (float*)d_ws;
    size_t off = 0;
    auto alloc = [&](size_t n) { float* p = ws + off; off += n; return p; };
    unsigned short* h1max = (unsigned short*)alloc((size_t)NN * H / 2);  // bf16, 67 MB
    unsigned short* W2t   = (unsigned short*)alloc(128 * 128 / 2);
    float* b2p     = alloc(H);
    float* graphsum= alloc((size_t)NB * H);
    float* c1raw   = alloc((size_t)NB * C1);
    float* zbuf    = alloc(NB);
    // atomic accumulators (contiguous; zeroed by one memset per iteration)
    const size_t ATOMN = (size_t)4 * NSH * H + 2 * C1 + 2;
    float* atomics = alloc(ATOMN);
    float* S1sh = atomics;
    float* Q1sh = S1sh + NSH * H;
    float* S2sh = Q1sh + NSH * H;
    float* Q2sh = S2sh + NSH * H;
    float* S3   = Q2sh + NSH * H;
    float* Q3   = S3 + C1;
    float* SzQz = Q3 + C1;

    hipMemsetAsync(atomics, 0, ATOMN * sizeof(float), stream);
    k_knn_mfma1<<<dim3(NB), dim3(512), 0, stream>>>(x, pos, W1, b1, h1max, S1sh, Q1sh);
    k_prep2<<<dim3(128), dim3(128), 0, stream>>>(W2, S1sh, Q1sh, g1, be1, b2, W2t, b2p);
    k_mfma2<<<dim3(NB), dim3(256), 0, stream>>>(h1max, W2t, b2p, graphsum, S2sh, Q2sh);
    k_cls1<<<dim3(256), dim3(256), 0, stream>>>(graphsum, S2sh, Q2sh, g2, be2, Wc1, bc1, c1raw, S3, Q3);
    k_cls2<<<dim3(256), dim3(256), 0, stream>>>(c1raw, S3, Q3, gc1, bec1, Wc2, bc2, zbuf, SzQz);
    k_final<<<dim3(16), dim3(256), 0, stream>>>(zbuf, SzQz, gc2, bec2, out);
}

// Round 9
// 236.938 us; speedup vs baseline: 1.0518x; 1.0518x over previous
//
#include <hip/hip_runtime.h>
#include <hip/hip_bf16.h>
#include <math.h>

// Problem constants
#define NB   4096      // graphs
#define MM   64        // points per graph
#define KNN  3
#define FX   59
#define H    128
#define NN   (NB*MM)       // 262144 nodes
#define NE   (NN*KNN)      // 786432 edges
#define C1   256
#define EPSB 1e-5f
#define NSH  16            // atomic shadow copies (contention = NB/NSH per addr)

typedef __attribute__((ext_vector_type(8))) short short8;   // 8 bf16 (4 VGPRs)
typedef __attribute__((ext_vector_type(4))) float f32x4;

__device__ __forceinline__ float wave_red(float v) {
#pragma unroll
    for (int m = 32; m >= 1; m >>= 1) v += __shfl_xor(v, m, 64);
    return v;
}

__device__ __forceinline__ void atomAddF(float* p, float v) {
    __hip_atomic_fetch_add(p, v, __ATOMIC_RELAXED, __HIP_MEMORY_SCOPE_AGENT);
}

__device__ __forceinline__ unsigned short f2bf(float f) {
    union { float f; unsigned u; } v; v.f = f;
    unsigned r = v.u + 0x7fffu + ((v.u >> 16) & 1u);   // round-to-nearest-even
    return (unsigned short)(r >> 16);
}

// pack two f32 -> u32 of 2 bf16 (lo = a, hi = b), RNE (v_cvt_pk_bf16_f32)
__device__ __forceinline__ unsigned int pack_bf2(float a, float b) {
    union { __hip_bfloat162 h; unsigned int u; } cv;
    cv.h = __float22bfloat162_rn(make_float2(a, b));
    return cv.u;
}

// ---------------------------------------------------------------------------
// K1, edge-matrix form (r7 base = best measured) + r9 fixes:
//  - kNN on packed u64 keys (bits(d)<<32 | j): one compare replaces the
//    (d,idx) lexicographic pair; merge is a branch-free sorted-triple
//    merge network. Same tie-break as jax top_k (d>=0 -> bits monotone).
//  - BN1 red buffer stride 17 (+1 pad): read banks 17*tid+mm mod 32 are a
//    permutation -> conflict-free (r7's stride 16 was 32-way on reads).
//  - NO granule rotation (r6/r8: neutral-to-negative), NO per-lane scattered
//    atomics (r8: +12MB write traffic, regression) — coalesced tid<128/256.
// 512 thr / 8 waves; LDS 38.9 KB -> 4 blocks/CU (32 waves, at wave cap).
// ---------------------------------------------------------------------------
__global__ __launch_bounds__(512, 8) void k_knn_mfma1(
    const float* __restrict__ x, const float* __restrict__ pos,
    const float* __restrict__ W1, const float* __restrict__ b1,
    unsigned short* __restrict__ h1max,
    float* __restrict__ S1sh, float* __restrict__ Q1sh)
{
    __shared__ float pos_s[MM * 3];
    __shared__ int   nbr_s[MM * 3];
    __shared__ float b1_s[H];
    __shared__ __align__(16) unsigned short a_s[MM * 72];       // [x|p|0,0] staging
    __shared__ __align__(16) unsigned short e_s[3 * MM * 72];   // edge features

    const int blk = blockIdx.x, tid = threadIdx.x;
    const float* xg = x + (size_t)blk * MM * FX;
    const float* pg = pos + (size_t)blk * MM * 3;

    // --- prepx: thread = one 16B granule of a node row
    {
        const int node = tid >> 3, c0g = (tid & 7) * 8;
        float v[8];
#pragma unroll
        for (int i = 0; i < 8; ++i) {
            int cI = c0g + i;
            v[i] = (cI < FX) ? xg[node * FX + cI]
                             : ((cI < 62) ? pg[node * 3 + (cI - FX)] : 0.f);
        }
        uint4 pk;
        pk.x = pack_bf2(v[0], v[1]); pk.y = pack_bf2(v[2], v[3]);
        pk.z = pack_bf2(v[4], v[5]); pk.w = pack_bf2(v[6], v[7]);
        *(uint4*)(a_s + node * 72 + c0g) = pk;
    }
    if (tid < MM * 3) pos_s[tid] = pg[tid];
    if (tid < H) b1_s[tid] = b1[tid];

    // --- W1 fragments straight from global (L2-hot)
    const int lane = tid & 63;
    const int w    = tid >> 6;          // 8 waves
    const int m    = lane & 15;
    const int kg   = lane >> 4;
    const int ch   = w * 16 + m;        // wave owns channels [w*16, w*16+16)

    short8 bfr[2];
#pragma unroll
    for (int kc = 0; kc < 2; ++kc) {
        float t8[8];
#pragma unroll
        for (int i = 0; i < 8; ++i) {
            int k = kc * 32 + kg * 8 + i;
            t8[i] = (k < 62) ? W1[k * H + ch] : 0.f;
        }
        uint4 pk;
        pk.x = pack_bf2(t8[0], t8[1]); pk.y = pack_bf2(t8[2], t8[3]);
        pk.z = pack_bf2(t8[4], t8[5]); pk.w = pack_bf2(t8[6], t8[7]);
        bfr[kc] = *(short8*)&pk;
    }
    __syncthreads();    // a_s, pos_s ready

    // --- parallel kNN, packed u64 keys: 8 threads/node, 8 candidates each;
    //     merge via shfl_xor(1,2,4) sorted-triple merge network.
    {
        const int node = tid >> 3, q = tid & 7;
        const float px = pos_s[node * 3 + 0];
        const float py = pos_s[node * 3 + 1];
        const float pz = pos_s[node * 3 + 2];
        unsigned long long k0 = ~0ull, k1 = ~0ull, k2 = ~0ull;
        for (int jj = 0; jj < 8; ++jj) {
            int j = q * 8 + jj;
            if (j == node) continue;
            float dx = pos_s[j * 3 + 0] - px;
            float dy = pos_s[j * 3 + 1] - py;
            float dz = pos_s[j * 3 + 2] - pz;
            float d = dx * dx + dy * dy + dz * dz;
            unsigned long long key =
                ((unsigned long long)__float_as_uint(d) << 32) | (unsigned)j;
            if (key < k2) {
                if (key < k1) {
                    k2 = k1;
                    if (key < k0) { k1 = k0; k0 = key; } else k1 = key;
                } else k2 = key;
            }
        }
#pragma unroll
        for (int mq = 1; mq <= 4; mq <<= 1) {
            unsigned long long e0 = __shfl_xor(k0, mq, 64);
            unsigned long long e1 = __shfl_xor(k1, mq, 64);
            unsigned long long e2 = __shfl_xor(k2, mq, 64);
            // both triples sorted; take 3 smallest of the merge:
            unsigned long long m0 = k0 < e0 ? k0 : e0;
            unsigned long long xx = k0 < e0 ? e0 : k0;   // max(a0,b0)
            unsigned long long yy = k1 < e1 ? k1 : e1;   // min(a1,b1)
            unsigned long long zz = k2 < e2 ? k2 : e2;   // min(a2,b2)
            unsigned long long m1 = xx < yy ? xx : yy;
            unsigned long long xy = xx < yy ? yy : xx;   // max(xx,yy)
            unsigned long long m2 = xy < zz ? xy : zz;
            k0 = m0; k1 = m1; k2 = m2;
        }
        if (q == 0) {
            nbr_s[node * 3 + 0] = (int)(unsigned)(k0 & 0xffffffffu);
            nbr_s[node * 3 + 1] = (int)(unsigned)(k1 & 0xffffffffu);
            nbr_s[node * 3 + 2] = (int)(unsigned)(k2 & 0xffffffffu);
        }
    }
    __syncthreads();    // nbr_s ready

    // --- E-build: row (slot*64+node) = a_s[j] with cols 59..61 patched to
    //     bf16(p_j - p_i), cols 62,63 = 0. 1536 granule tasks / 512 thr.
#pragma unroll
    for (int it = 0; it < 3; ++it) {
        const int T = tid + it * 512;
        const int row = T >> 3, g = T & 7;
        const int node = row & 63, slot = row >> 6;
        const int j = nbr_s[node * 3 + slot];
        if (g < 7) {
            *(uint4*)(e_s + row * 72 + g * 8) = *(const uint4*)(a_s + j * 72 + g * 8);
        } else {
            uint4 v = *(const uint4*)(a_s + j * 72 + 56);   // cols 56..63
            float r0 = pos_s[j * 3 + 0] - pos_s[node * 3 + 0];
            float r1 = pos_s[j * 3 + 1] - pos_s[node * 3 + 1];
            float r2 = pos_s[j * 3 + 2] - pos_s[node * 3 + 2];
            v.y = (v.y & 0xffffu) | ((unsigned)f2bf(r0) << 16);  // col59 (58 kept)
            v.z = pack_bf2(r1, r2);                              // cols 60,61
            v.w = 0u;                                            // cols 62,63
            *(uint4*)(e_s + row * 72 + 56) = v;
        }
    }
    __syncthreads();    // e_s ready

    // --- MFMA E@W1 per node-group; in-register relu/max/stats epilogue.
    const int cb = w * 16 + kg * 4;          // 4 consecutive channels per lane
    const float b1v0 = b1_s[cb + 0], b1v1 = b1_s[cb + 1];
    const float b1v2 = b1_s[cb + 2], b1v3 = b1_s[cb + 3];
    float s0 = 0.f, s1 = 0.f, s2 = 0.f, s3 = 0.f;
    float q0 = 0.f, q1 = 0.f, q2 = 0.f, q3 = 0.f;
    unsigned int* hout32 = (unsigned int*)(h1max + (size_t)blk * MM * H);
#pragma unroll
    for (int rt4 = 0; rt4 < 4; ++rt4) {
        const int node = rt4 * 16 + m;
        f32x4 acc0 = (f32x4){0.f,0.f,0.f,0.f};
        f32x4 acc1 = (f32x4){0.f,0.f,0.f,0.f};
        f32x4 acc2 = (f32x4){0.f,0.f,0.f,0.f};
#pragma unroll
        for (int kc = 0; kc < 2; ++kc) {
            const int ko = kc * 32 + kg * 8;
            short8 a0 = *(const short8*)(e_s + (node      ) * 72 + ko);
            short8 a1 = *(const short8*)(e_s + (node +  64) * 72 + ko);
            short8 a2 = *(const short8*)(e_s + (node + 128) * 72 + ko);
            acc0 = __builtin_amdgcn_mfma_f32_16x16x32_bf16(bfr[kc], a0, acc0, 0, 0, 0);
            acc1 = __builtin_amdgcn_mfma_f32_16x16x32_bf16(bfr[kc], a1, acc1, 0, 0, 0);
            acc2 = __builtin_amdgcn_mfma_f32_16x16x32_bf16(bfr[kc], a2, acc2, 0, 0, 0);
        }
        float hm0, hm1, hm2, hm3;
        {
            float ha = fmaxf(acc0[0] + b1v0, 0.f), hb = fmaxf(acc1[0] + b1v0, 0.f), hc = fmaxf(acc2[0] + b1v0, 0.f);
            s0 += ha + hb + hc; q0 += ha * ha + hb * hb + hc * hc; hm0 = fmaxf(fmaxf(ha, hb), hc);
        }
        {
            float ha = fmaxf(acc0[1] + b1v1, 0.f), hb = fmaxf(acc1[1] + b1v1, 0.f), hc = fmaxf(acc2[1] + b1v1, 0.f);
            s1 += ha + hb + hc; q1 += ha * ha + hb * hb + hc * hc; hm1 = fmaxf(fmaxf(ha, hb), hc);
        }
        {
            float ha = fmaxf(acc0[2] + b1v2, 0.f), hb = fmaxf(acc1[2] + b1v2, 0.f), hc = fmaxf(acc2[2] + b1v2, 0.f);
            s2 += ha + hb + hc; q2 += ha * ha + hb * hb + hc * hc; hm2 = fmaxf(fmaxf(ha, hb), hc);
        }
        {
            float ha = fmaxf(acc0[3] + b1v3, 0.f), hb = fmaxf(acc1[3] + b1v3, 0.f), hc = fmaxf(acc2[3] + b1v3, 0.f);
            s3 += ha + hb + hc; q3 += ha * ha + hb * hb + hc * hc; hm3 = fmaxf(fmaxf(ha, hb), hc);
        }
        uint2 val;
        val.x = pack_bf2(hm0, hm1);
        val.y = pack_bf2(hm2, hm3);
        *(uint2*)(hout32 + node * 64 + w * 8 + kg * 2) = val;
    }
    __syncthreads();    // all e_s reads done; reuse as reduction buffer

    // --- BN1 partial reduce: red[ch*17 + m] (stride-17 pad: read banks are a
    //     permutation of 32 -> conflict-free; r7's stride-16 was 32-way).
    float* red = (float*)e_s;   // 2*2176 floats = 17.4 KB <= 27.6 KB
    red[(cb + 0) * 17 + m] = s0;
    red[(cb + 1) * 17 + m] = s1;
    red[(cb + 2) * 17 + m] = s2;
    red[(cb + 3) * 17 + m] = s3;
    red[2176 + (cb + 0) * 17 + m] = q0;
    red[2176 + (cb + 1) * 17 + m] = q1;
    red[2176 + (cb + 2) * 17 + m] = q2;
    red[2176 + (cb + 3) * 17 + m] = q3;
    __syncthreads();
    const int sel = blk & (NSH - 1);
    if (tid < H) {
        float S = 0.f;
#pragma unroll
        for (int mm = 0; mm < 16; ++mm) S += red[tid * 17 + mm];
        atomAddF(&S1sh[sel * H + tid], S);
    } else if (tid < 2 * H) {
        const int t2 = tid - H;
        float Q = 0.f;
#pragma unroll
        for (int mm = 0; mm < 16; ++mm) Q += red[2176 + t2 * 17 + mm];
        atomAddF(&Q1sh[sel * H + t2], Q);
    }
}

// ---------------------------------------------------------------------------
// prep2: fold 16 BN1 shadows -> affine1 in-register; emit W2t (affine folded)
// and b2p. grid=128, blk=128.
// ---------------------------------------------------------------------------
__global__ __launch_bounds__(128) void k_prep2(
    const float* __restrict__ W2, const float* __restrict__ S1sh,
    const float* __restrict__ Q1sh, const float* __restrict__ g1,
    const float* __restrict__ be1, const float* __restrict__ b2,
    unsigned short* __restrict__ W2t, float* __restrict__ b2p)
{
    const int n = blockIdx.x, k = threadIdx.x;
    float S = 0.f, Q = 0.f;
#pragma unroll
    for (int i = 0; i < NSH; ++i) { S += S1sh[i * H + k]; Q += Q1sh[i * H + k]; }
    float mu  = S * (1.f / (float)NE);
    float var = Q * (1.f / (float)NE) - mu * mu;
    float a   = g1[k] * rsqrtf(var + EPSB);
    float cc  = be1[k] - mu * a;
    float wv  = W2[k * H + n];
    W2t[n * H + k] = f2bf(a * wv);
    float contrib = wave_red(cc * wv);
    __shared__ float red2[2];
    if ((k & 63) == 0) red2[k >> 6] = contrib;
    __syncthreads();
    if (k == 0) b2p[n] = b2[n] + red2[0] + red2[1];
}

// ---------------------------------------------------------------------------
// K3: h2 = relu(h1max(bf16) @ W2t + b2p) via MFMA; graphsum + shadowed
// atomic BN2 stats. LDS-staged. grid=4096, 256 thr.
// ---------------------------------------------------------------------------
__global__ __launch_bounds__(256) void k_mfma2(
    const unsigned short* __restrict__ h1max, const unsigned short* __restrict__ W2t,
    const float* __restrict__ b2p,
    float* __restrict__ graphsum, float* __restrict__ S2sh, float* __restrict__ Q2sh)
{
    __shared__ __align__(16) unsigned short a_s[MM * 136];  // 64x128 bf16, stride 136
    const int blk = blockIdx.x, tid = threadIdx.x;
    const unsigned short* hg = h1max + (size_t)blk * MM * H;
    for (int t = tid; t < MM * H / 8; t += 256) {
        int row = t >> 4, col8 = (t & 15) * 8;
        *(short8*)(a_s + row * 136 + col8) = *(const short8*)(hg + row * H + col8);
    }
    __syncthreads();

    const int lane = tid & 63, w = tid >> 6, wcol = w * 32;
    const int m = lane & 15, kg = lane >> 4;

    short8 bfr[2][4];
#pragma unroll
    for (int ct = 0; ct < 2; ++ct)
#pragma unroll
        for (int kc = 0; kc < 4; ++kc)
            bfr[ct][kc] = *(const short8*)(W2t + (wcol + ct * 16 + m) * H + kc * 32 + kg * 8);

    f32x4 acc[4][2];
#pragma unroll
    for (int rt = 0; rt < 4; ++rt)
#pragma unroll
        for (int ct = 0; ct < 2; ++ct) acc[rt][ct] = (f32x4){0.f, 0.f, 0.f, 0.f};

#pragma unroll
    for (int kc = 0; kc < 4; ++kc)
#pragma unroll
        for (int rt = 0; rt < 4; ++rt) {
            short8 a = *(const short8*)(a_s + (rt * 16 + m) * 136 + kc * 32 + kg * 8);
#pragma unroll
            for (int ct = 0; ct < 2; ++ct)
                acc[rt][ct] = __builtin_amdgcn_mfma_f32_16x16x32_bf16(a, bfr[ct][kc], acc[rt][ct], 0, 0, 0);
        }

    const int sel = blk & (NSH - 1);
#pragma unroll
    for (int ct = 0; ct < 2; ++ct) {
        float bv = b2p[wcol + ct * 16 + m];
        float s = 0.f, q = 0.f;
#pragma unroll
        for (int rt = 0; rt < 4; ++rt)
#pragma unroll
            for (int r = 0; r < 4; ++r) {
                float v = fmaxf(acc[rt][ct][r] + bv, 0.f);
                s += v; q += v * v;
            }
        s += __shfl_xor(s, 16, 64); q += __shfl_xor(q, 16, 64);
        s += __shfl_xor(s, 32, 64); q += __shfl_xor(q, 32, 64);
        if (lane < 16) {
            int col = wcol + ct * 16 + lane;
            graphsum[(size_t)blk * H + col] = s;
            atomAddF(&S2sh[sel * H + col], s);
            atomAddF(&Q2sh[sel * H + col], q);
        }
    }
}

// ---------------------------------------------------------------------------
// cls1: affine2 inline from shadows; pooled = BN2(graphsum/64);
// c1 = ReLU(pooled @ Wc1 + bc1); BN3 stats via direct atomics.
// grid=256, blk=256 (16 graphs per block).
// ---------------------------------------------------------------------------
__global__ __launch_bounds__(256) void k_cls1(
    const float* __restrict__ graphsum,
    const float* __restrict__ S2sh, const float* __restrict__ Q2sh,
    const float* __restrict__ g2, const float* __restrict__ be2,
    const float* __restrict__ Wc1, const float* __restrict__ bc1,
    float* __restrict__ c1raw, float* __restrict__ S3, float* __restrict__ Q3)
{
    __shared__ float a2_s[H], c2_s[H];
    const int blk = blockIdx.x, tid = threadIdx.x;
    if (tid < H) {
        float S = 0.f, Q = 0.f;
#pragma unroll
        for (int i = 0; i < NSH; ++i) { S += S2sh[i * H + tid]; Q += Q2sh[i * H + tid]; }
        float mu  = S * (1.f / (float)NN);
        float var = Q * (1.f / (float)NN) - mu * mu;
        float a   = g2[tid] * rsqrtf(var + EPSB);
        a2_s[tid] = a;
        c2_s[tid] = be2[tid] - mu * a;
    }
    __syncthreads();
    __shared__ float pooled_s[16 * H];
    const int g0 = blk * 16;
    for (int t = tid; t < 16 * H; t += 256) {
        int f = t & 127;
        pooled_s[t] = a2_s[f] * (graphsum[(size_t)g0 * H + t] * (1.f / 64.f)) + c2_s[f];
    }
    __syncthreads();
    const int c = tid;
    float acc[16];
    const float bias = bc1[c];
#pragma unroll
    for (int gi = 0; gi < 16; ++gi) acc[gi] = bias;
    for (int f = 0; f < H; ++f) {
        float wv = Wc1[f * C1 + c];
#pragma unroll
        for (int gi = 0; gi < 16; ++gi) acc[gi] += pooled_s[gi * H + f] * wv;
    }
    float s = 0.f, q = 0.f;
#pragma unroll
    for (int gi = 0; gi < 16; ++gi) {
        float h = fmaxf(acc[gi], 0.f);
        c1raw[(size_t)(g0 + gi) * C1 + c] = h;
        s += h; q += h * h;
    }
    atomAddF(&S3[c], s);
    atomAddF(&Q3[c], q);
}

// ---------------------------------------------------------------------------
// cls2: affine3 inline from S3/Q3; z = ReLU(BN3(c1) @ Wc2 + bc2);
// final-BN scalar stats via atomics. grid=256, blk=256 (16 lanes/graph).
// ---------------------------------------------------------------------------
__global__ __launch_bounds__(256) void k_cls2(
    const float* __restrict__ c1raw,
    const float* __restrict__ S3, const float* __restrict__ Q3,
    const float* __restrict__ gc1, const float* __restrict__ bec1,
    const float* __restrict__ Wc2, const float* __restrict__ bc2,
    float* __restrict__ z, float* __restrict__ SzQz)
{
    __shared__ float a3_s[C1], c3_s[C1], w3_s[C1];
    __shared__ float zloc[16];
    const int blk = blockIdx.x, tid = threadIdx.x;
    {
        float S = S3[tid], Q = Q3[tid];
        float mu  = S * (1.f / (float)NB);
        float var = Q * (1.f / (float)NB) - mu * mu;
        float a   = gc1[tid] * rsqrtf(var + EPSB);
        a3_s[tid] = a;
        c3_s[tid] = bec1[tid] - mu * a;
        w3_s[tid] = Wc2[tid];
    }
    __syncthreads();
    const int g0 = blk * 16;
    {
        const int gi = tid >> 4, part = tid & 15;
        const float* crow = c1raw + (size_t)(g0 + gi) * C1 + part * 16;
        float acc3 = 0.f;
#pragma unroll
        for (int i = 0; i < 16; i += 4) {
            float4 cv = *(const float4*)(crow + i);
            int f = part * 16 + i;
            acc3 += (a3_s[f + 0] * cv.x + c3_s[f + 0]) * w3_s[f + 0];
            acc3 += (a3_s[f + 1] * cv.y + c3_s[f + 1]) * w3_s[f + 1];
            acc3 += (a3_s[f + 2] * cv.z + c3_s[f + 2]) * w3_s[f + 2];
            acc3 += (a3_s[f + 3] * cv.w + c3_s[f + 3]) * w3_s[f + 3];
        }
#pragma unroll
        for (int mm = 1; mm <= 8; mm <<= 1) acc3 += __shfl_xor(acc3, mm, 64);
        if (part == 0) zloc[gi] = fmaxf(acc3 + bc2[0], 0.f);
    }
    __syncthreads();
    if (tid < 16) z[g0 + tid] = zloc[tid];
    if (tid == 0) {
        float s = 0.f, q = 0.f;
#pragma unroll
        for (int i = 0; i < 16; ++i) { float zz = zloc[i]; s += zz; q += zz * zz; }
        atomAddF(&SzQz[0], s);
        atomAddF(&SzQz[1], q);
    }
}

// ---------------------------------------------------------------------------
// final: BN over 4096 z (stats from SzQz) + sigmoid. grid=16, blk=256.
// ---------------------------------------------------------------------------
__global__ __launch_bounds__(256) void k_final(
    const float* __restrict__ z, const float* __restrict__ SzQz,
    const float* __restrict__ gc2, const float* __restrict__ bec2,
    float* __restrict__ out)
{
    const int g = blockIdx.x * 256 + threadIdx.x;
    float S = SzQz[0], Q = SzQz[1];
    float mu  = S * (1.f / 4096.f);
    float var = Q * (1.f / 4096.f) - mu * mu;
    float a   = gc2[0] * rsqrtf(var + EPSB);
    float cb  = bec2[0] - mu * a;
    float v = a * z[g] + cb;
    out[g] = 1.f / (1.f + expf(-v));
}

extern "C" void kernel_launch(void* const* d_in, const int* in_sizes, int n_in,
                              void* d_out, int out_size, void* d_ws, size_t ws_size,
                              hipStream_t stream)
{
    const float* x    = (const float*)d_in[0];
    const float* pos  = (const float*)d_in[1];
    // d_in[2] = batch (int32) — graphs are contiguous 64-node chunks; unused
    const float* W1   = (const float*)d_in[3];
    const float* b1   = (const float*)d_in[4];
    const float* g1   = (const float*)d_in[5];
    const float* be1  = (const float*)d_in[6];
    const float* W2   = (const float*)d_in[7];
    const float* b2   = (const float*)d_in[8];
    const float* g2   = (const float*)d_in[9];
    const float* be2  = (const float*)d_in[10];
    const float* Wc1  = (const float*)d_in[11];
    const float* bc1  = (const float*)d_in[12];
    const float* gc1  = (const float*)d_in[13];
    const float* bec1 = (const float*)d_in[14];
    const float* Wc2  = (const float*)d_in[15];
    const float* bc2  = (const float*)d_in[16];
    const float* gc2  = (const float*)d_in[17];
    const float* bec2 = (const float*)d_in[18];
    float* out = (float*)d_out;

    float* ws = (float*)d_ws;
    size_t off = 0;
    auto alloc = [&](size_t n) { float* p = ws + off; off += n; return p; };
    unsigned short* h1max = (unsigned short*)alloc((size_t)NN * H / 2);  // bf16, 67 MB
    unsigned short* W2t   = (unsigned short*)alloc(128 * 128 / 2);
    float* b2p     = alloc(H);
    float* graphsum= alloc((size_t)NB * H);
    float* c1raw   = alloc((size_t)NB * C1);
    float* zbuf    = alloc(NB);
    // atomic accumulators (contiguous; zeroed by one memset per iteration)
    const size_t ATOMN = (size_t)4 * NSH * H + 2 * C1 + 2;
    float* atomics = alloc(ATOMN);
    float* S1sh = atomics;
    float* Q1sh = S1sh + NSH * H;
    float* S2sh = Q1sh + NSH * H;
    float* Q2sh = S2sh + NSH * H;
    float* S3   = Q2sh + NSH * H;
    float* Q3   = S3 + C1;
    float* SzQz = Q3 + C1;

    hipMemsetAsync(atomics, 0, ATOMN * sizeof(float), stream);
    k_knn_mfma1<<<dim3(NB), dim3(512), 0, stream>>>(x, pos, W1, b1, h1max, S1sh, Q1sh);
    k_prep2<<<dim3(128), dim3(128), 0, stream>>>(W2, S1sh, Q1sh, g1, be1, b2, W2t, b2p);
    k_mfma2<<<dim3(NB), dim3(256), 0, stream>>>(h1max, W2t, b2p, graphsum, S2sh, Q2sh);
    k_cls1<<<dim3(256), dim3(256), 0, stream>>>(graphsum, S2sh, Q2sh, g2, be2, Wc1, bc1, c1raw, S3, Q3);
    k_cls2<<<dim3(256), dim3(256), 0, stream>>>(c1raw, S3, Q3, gc1, bec1, Wc2, bc2, zbuf, SzQz);
    k_final<<<dim3(16), dim3(256), 0, stream>>>(zbuf, SzQz, gc2, bec2, out);
}